// Round 13
// baseline (149.036 us; speedup 1.0000x reference)
//
#include <hip/hip_runtime.h>
#include <hip/hip_bf16.h>
#include <cstdint>
#include <cstddef>

#define I_F   1024
#define O_F   1024
#define BATCH 4096
#define KDIM  9216   // 9 * 1024 : j-major (j=0 base/swish, j=1..8 spline bases)
#define EPSC  1e-7f

typedef __bf16 bf16;
typedef __bf16 bf16x4 __attribute__((ext_vector_type(4)));
typedef __bf16 bf16x8 __attribute__((ext_vector_type(8)));
typedef float  f32x4  __attribute__((ext_vector_type(4)));
typedef float  f32x16 __attribute__((ext_vector_type(16)));

// ---------------------------------------------------------------------------
// Kernel 1: activations A[b][j*1024+i] = {swish(x), bases[0..7]}  (bf16)
// ---------------------------------------------------------------------------
__global__ __launch_bounds__(256) void act_kernel(const float* __restrict__ x,
                                                  const float* __restrict__ grid,
                                                  bf16* __restrict__ A) {
    int t  = blockIdx.x * 256 + threadIdx.x;     // 1,048,576 threads
    int b  = t >> 8;
    int i0 = (t & 255) << 2;
    f32x4 xv4 = *(const f32x4*)(x + (size_t)b * I_F + i0);

    float g[12];
#pragma unroll
    for (int j = 0; j < 12; ++j) g[j] = grid[j];
    float r1[11], r2[10], r3[9];
#pragma unroll
    for (int j = 0; j < 11; ++j) r1[j] = __builtin_amdgcn_rcpf(g[j + 1] - g[j] + EPSC);
#pragma unroll
    for (int j = 0; j < 10; ++j) r2[j] = __builtin_amdgcn_rcpf(g[j + 2] - g[j] + EPSC);
#pragma unroll
    for (int j = 0; j < 9;  ++j) r3[j] = __builtin_amdgcn_rcpf(g[j + 3] - g[j] + EPSC);

    float sw[4];
    float bs8[4][8];
#pragma unroll
    for (int e = 0; e < 4; ++e) {
        float xv = xv4[e];
        float bas[11];
#pragma unroll
        for (int j = 0; j < 11; ++j)
            bas[j] = (xv >= g[j] && xv < g[j + 1]) ? 1.0f : 0.0f;
#pragma unroll
        for (int j = 0; j < 10; ++j)
            bas[j] = (xv - g[j]) * r1[j] * bas[j] + (g[j + 2] - xv) * r1[j + 1] * bas[j + 1];
#pragma unroll
        for (int j = 0; j < 9; ++j)
            bas[j] = (xv - g[j]) * r2[j] * bas[j] + (g[j + 3] - xv) * r2[j + 1] * bas[j + 1];
#pragma unroll
        for (int j = 0; j < 8; ++j)
            bas[j] = (xv - g[j]) * r3[j] * bas[j] + (g[j + 4] - xv) * r3[j + 1] * bas[j + 1];
#pragma unroll
        for (int k = 0; k < 8; ++k) bs8[e][k] = bas[k];
        float sig = 1.0f / (1.0f + __expf(-xv));
        sw[e] = xv * sig;
    }

    bf16* outp = A + (size_t)b * KDIM + i0;
    *(bf16x4*)(outp) = (bf16x4){(bf16)sw[0], (bf16)sw[1], (bf16)sw[2], (bf16)sw[3]};
#pragma unroll
    for (int k = 0; k < 8; ++k)
        *(bf16x4*)(outp + (size_t)(k + 1) * 1024) =
            (bf16x4){(bf16)bs8[0][k], (bf16)bs8[1][k], (bf16)bs8[2][k], (bf16)bs8[3][k]};
}

// ---------------------------------------------------------------------------
// Kernel 2: Wt[o][j*1024+i] = { base_scaler[i,o], spline_weight[i,o,k]*spline_scaler[i,o] }
// ---------------------------------------------------------------------------
__global__ __launch_bounds__(256) void wprep_kernel(const float* __restrict__ w,
                                                    const float* __restrict__ ss,
                                                    const float* __restrict__ bs,
                                                    bf16* __restrict__ Wt) {
    int g = blockIdx.x * 256 + threadIdx.x;      // 1024 i * 128 o-groups = 131072
    int i  = g & 1023;
    int o0 = (g >> 10) << 3;                     // 8 o per thread
    size_t io0 = (size_t)i * 1024 + o0;
    f32x4 ssv0 = *(const f32x4*)(ss + io0);
    f32x4 ssv1 = *(const f32x4*)(ss + io0 + 4);
    f32x4 bsv0 = *(const f32x4*)(bs + io0);
    f32x4 bsv1 = *(const f32x4*)(bs + io0 + 4);
#pragma unroll
    for (int oo = 0; oo < 8; ++oo) {
        int o = o0 + oo;
        float scale = (oo < 4) ? ssv0[oo & 3] : ssv1[oo & 3];
        float base  = (oo < 4) ? bsv0[oo & 3] : bsv1[oo & 3];
        const float* wp = w + (io0 + oo) * 8;
        f32x4 w0 = *(const f32x4*)(wp);
        f32x4 w1 = *(const f32x4*)(wp + 4);

        bf16* outp = Wt + (size_t)o * KDIM + i;
        outp[0] = (bf16)base;
#pragma unroll
        for (int k = 0; k < 4; ++k) outp[(size_t)(k + 1) * 1024] = (bf16)(w0[k] * scale);
#pragma unroll
        for (int k = 0; k < 4; ++k) outp[(size_t)(k + 5) * 1024] = (bf16)(w1[k] * scale);
    }
}

// ---------------------------------------------------------------------------
// Kernel 3: GEMM  out = A(4096x9216) * Wt^T(1024x9216), bf16 MFMA 32x32x16.
// R13: per-wave shape IDENTICAL to proven R12 (128x64 output/wave, 12 frag
// ds_reads need-order, 16-MFMA cluster, same swizzle pair, reads-first), but
// block = 4 waves (256 thr), tile 256x128, TRIPLE-buffer 72KB LDS ->
// 2 blocks/CU (cross-block overlap absorbs barrier/wait convergence).
// Depth-2 counted vmcnt(6) (6 DMA/wave/tile). Grid 16tm x 8tn x 4s = 512;
// decode tn == XCD (Wt panel 2.36MB L2-resident per XCD).
// ---------------------------------------------------------------------------
__device__ __forceinline__ void load_lds16(const bf16* g, bf16* l) {
    __builtin_amdgcn_global_load_lds(
        (__attribute__((address_space(1))) void*)g,
        (__attribute__((address_space(3))) void*)l, 16, 0, 0);
}

__global__ __launch_bounds__(256, 2) void gemm_kernel(const bf16* __restrict__ A,
                                                      const bf16* __restrict__ Wt,
                                                      bf16* __restrict__ parts,
                                                      int split, int ktiles) {  // BK=32 units
    __shared__ __align__(16) bf16 SA[3][8192];   // 3 slots x 16KB (256 rows x 32 k)
    __shared__ __align__(16) bf16 SB[3][4096];   // 3 slots x  8KB (128 rows x 32 k)

    const int t    = threadIdx.x;
    const int lane = t & 63;
    const int w    = t >> 6;           // 0..3

    // Decode: tn == XCD. bid = 0..511; i = s*16 + tm within the XCD.
    const int tn = blockIdx.x & 7;
    const int i  = blockIdx.x >> 3;    // 0..63
    const int s  = i >> 4;             // split index 0..3
    const int tm = i & 15;

    const int row0 = tm << 8;          // 256-row tile
    const int col0 = tn << 7;          // 128-col tile
    const size_t k0 = (size_t)s * ktiles * 32;

    // ---- staging (linear LDS dest; pre-swizzled global source) ----
    // content(phys unit p, row r) = logical unit p ^ ((r>>1)&3)
    const int sr = lane >> 2;                         // 0..15
    const int lc = (lane & 3) ^ ((lane >> 3) & 3);    // pre-swizzled 16B-unit
    const bf16* gA0 = A  + (size_t)(row0 + w * 16 + sr) * KDIM + k0 + lc * 8;
    const bf16* gB0 = Wt + (size_t)(col0 + w * 16 + sr) * KDIM + k0 + lc * 8;

    // ---- fragment read coords (2M x 2N wave grid) ----
    const int wm  = w >> 1;            // 0..1  (M half: 128 rows)
    const int wn  = w & 1;             // 0..1  (N half: 64 cols)
    const int r31 = lane & 31;
    const int hi  = lane >> 5;
    const int swb = (r31 >> 1) & 3;    // read-side swizzle (row bits 1-2)

    f32x16 acc[4][2];
#pragma unroll
    for (int mt = 0; mt < 4; ++mt)
#pragma unroll
        for (int nt = 0; nt < 2; ++nt)
#pragma unroll
            for (int r = 0; r < 16; ++r) acc[mt][nt][r] = 0.f;

    auto stage = [&](int j) {
        const int sl = j % 3;
        const bf16* pa = gA0 + (size_t)j * 32;
        const bf16* pb = gB0 + (size_t)j * 32;
#pragma unroll
        for (int q = 0; q < 4; ++q)    // A: 256 rows = 4 waves x 4 instr x 16 rows
            load_lds16(pa + (size_t)(q * 64) * KDIM, &SA[sl][(q * 64 + w * 16) * 32]);
#pragma unroll
        for (int q = 0; q < 2; ++q)    // B: 128 rows = 4 waves x 2 instr x 16 rows
            load_lds16(pb + (size_t)(q * 64) * KDIM, &SB[sl][(q * 64 + w * 16) * 32]);
    };

    // Reads issued in MFMA-need order for one ks slice.
    auto frag_load_ks = [&](int sl, int ks, bf16x8 (&af)[4], bf16x8 (&bv)[2]) {
        const int cp = ((ks * 2 + hi) ^ swb) << 3;
        af[0] = *(const bf16x8*)&SA[sl][(wm * 128 +  0 + r31) * 32 + cp];
        bv[0] = *(const bf16x8*)&SB[sl][(wn * 64  +  0 + r31) * 32 + cp];
        af[1] = *(const bf16x8*)&SA[sl][(wm * 128 + 32 + r31) * 32 + cp];
        bv[1] = *(const bf16x8*)&SB[sl][(wn * 64  + 32 + r31) * 32 + cp];
        af[2] = *(const bf16x8*)&SA[sl][(wm * 128 + 64 + r31) * 32 + cp];
        af[3] = *(const bf16x8*)&SA[sl][(wm * 128 + 96 + r31) * 32 + cp];
    };

    auto do_mfma = [&](bf16x8 (&af0)[4], bf16x8 (&bv0)[2],
                       bf16x8 (&af1)[4], bf16x8 (&bv1)[2]) {
        __builtin_amdgcn_s_setprio(1);
#pragma unroll
        for (int mt = 0; mt < 4; ++mt)
#pragma unroll
            for (int nt = 0; nt < 2; ++nt)
                acc[mt][nt] = __builtin_amdgcn_mfma_f32_32x32x16_bf16(
                    af0[mt], bv0[nt], acc[mt][nt], 0, 0, 0);
#pragma unroll
        for (int mt = 0; mt < 4; ++mt)
#pragma unroll
            for (int nt = 0; nt < 2; ++nt)
                acc[mt][nt] = __builtin_amdgcn_mfma_f32_32x32x16_bf16(
                    af1[mt], bv1[nt], acc[mt][nt], 0, 0, 0);
        __builtin_amdgcn_s_setprio(0);
    };

    // Prologue: 2 K-tiles in flight (6 loads/wave each).
    stage(0); stage(1);

    int j = 0;
    for (; j < ktiles - 2; ++j) {
        asm volatile("s_waitcnt vmcnt(6)" ::: "memory");   // tile j landed; j+1 in flight
        __builtin_amdgcn_s_barrier();                      // all waves see tile j
        asm volatile("" ::: "memory");                     // no read hoist above bar
        bf16x8 af0[4], bv0[2], af1[4], bv1[2];
        frag_load_ks(j % 3, 0, af0, bv0);                  // reads issued FIRST
        frag_load_ks(j % 3, 1, af1, bv1);
        stage(j + 2);                                      // slot freed at tile j-1
        do_mfma(af0, bv0, af1, bv1);                       // compiler interleaves
    }
    {
        asm volatile("s_waitcnt vmcnt(6)" ::: "memory");
        __builtin_amdgcn_s_barrier();
        asm volatile("" ::: "memory");
        bf16x8 af0[4], bv0[2], af1[4], bv1[2];
        frag_load_ks(j % 3, 0, af0, bv0);
        frag_load_ks(j % 3, 1, af1, bv1);
        do_mfma(af0, bv0, af1, bv1);
        ++j;
    }
    {
        asm volatile("s_waitcnt vmcnt(0)" ::: "memory");
        __builtin_amdgcn_s_barrier();
        asm volatile("" ::: "memory");
        bf16x8 af0[4], bv0[2], af1[4], bv1[2];
        frag_load_ks(j % 3, 0, af0, bv0);
        frag_load_ks(j % 3, 1, af1, bv1);
        do_mfma(af0, bv0, af1, bv1);
    }

    // Epilogue (UNIFORM): bf16 partial for every split s.
    // 32x32 C/D layout: col=lane&31, row=(reg&3)+8*(reg>>2)+4*(lane>>5) [m74/m101]
    bf16* cp = parts + (size_t)s * BATCH * O_F
             + (size_t)(row0 + wm * 128) * O_F + col0 + wn * 64 + r31;
#pragma unroll
    for (int mt = 0; mt < 4; ++mt)
#pragma unroll
        for (int nt = 0; nt < 2; ++nt)
#pragma unroll
            for (int r = 0; r < 16; ++r) {
                int rl = (r & 3) + 8 * (r >> 2) + 4 * hi;
                cp[(size_t)(mt * 32 + rl) * O_F + nt * 32] = (bf16)acc[mt][nt][r];
            }
}

// ---------------------------------------------------------------------------
// Kernel 4: out = sum(parts[0..np))   (split-K reduce), bf16 partials -> f32
// ---------------------------------------------------------------------------
__global__ __launch_bounds__(256) void add_kernel(float* __restrict__ out,
                                                  const bf16* __restrict__ parts,
                                                  int np) {
    int t = blockIdx.x * 256 + threadIdx.x;      // 1,048,576 threads, 4 f32 each
    f32x4 a = {0.f, 0.f, 0.f, 0.f};
    for (int p = 0; p < np; ++p) {
        bf16x4 b = *((const bf16x4*)(parts + (size_t)p * BATCH * O_F) + t);
#pragma unroll
        for (int e = 0; e < 4; ++e) a[e] += (float)b[e];
    }
    *((f32x4*)out + t) = a;
}

// ---------------------------------------------------------------------------
extern "C" void kernel_launch(void* const* d_in, const int* in_sizes, int n_in,
                              void* d_out, int out_size, void* d_ws, size_t ws_size,
                              hipStream_t stream) {
    const float* x    = (const float*)d_in[0];
    const float* grid = (const float*)d_in[1];
    const float* w    = (const float*)d_in[2];
    const float* ss   = (const float*)d_in[3];
    const float* bs   = (const float*)d_in[4];
    float* out = (float*)d_out;

    const size_t nA = (size_t)BATCH * KDIM * 2;   // 75.5 MB
    const size_t nW = (size_t)O_F   * KDIM * 2;   // 18.9 MB
    const size_t nP = (size_t)BATCH * O_F  * 2;   // 8.39 MB per bf16 partial

    bf16* A  = (bf16*)d_ws;
    bf16* Wt = (bf16*)((char*)d_ws + nA);
    bf16* parts = (bf16*)((char*)d_ws + nA + nW);

    act_kernel<<<(BATCH * I_F / 4) / 256, 256, 0, stream>>>(x, grid, A);
    wprep_kernel<<<(I_F * O_F / 8) / 256, 256, 0, stream>>>(w, ss, bs, Wt);

    // 16 tm x 8 tn x 4 splits = 512 blocks (tn == XCD), 2 blocks/CU.
    gemm_kernel<<<512, 256, 0, stream>>>(A, Wt, parts, 4, 72);
    add_kernel<<<(BATCH * O_F / 4) / 256, 256, 0, stream>>>(out, parts, 4);
}

// Round 14
// 118.661 us; speedup vs baseline: 1.2560x; 1.2560x over previous
//
#include <hip/hip_runtime.h>
#include <hip/hip_bf16.h>
#include <cstdint>
#include <cstddef>

#define I_F   1024
#define O_F   1024
#define BATCH 4096
#define KDIM  9216   // 9 * 1024 : j-major (j=0 base/swish, j=1..8 spline bases)
#define EPSC  1e-7f

typedef __bf16 bf16;
typedef __bf16 bf16x4 __attribute__((ext_vector_type(4)));
typedef __bf16 bf16x8 __attribute__((ext_vector_type(8)));
typedef float  f32x4  __attribute__((ext_vector_type(4)));

// ---------------------------------------------------------------------------
// Kernel 1: activations A[b][j*1024+i] = {swish(x), bases[0..7]}  (bf16)
// ---------------------------------------------------------------------------
__global__ __launch_bounds__(256) void act_kernel(const float* __restrict__ x,
                                                  const float* __restrict__ grid,
                                                  bf16* __restrict__ A) {
    int t  = blockIdx.x * 256 + threadIdx.x;     // 1,048,576 threads
    int b  = t >> 8;
    int i0 = (t & 255) << 2;
    f32x4 xv4 = *(const f32x4*)(x + (size_t)b * I_F + i0);

    float g[12];
#pragma unroll
    for (int j = 0; j < 12; ++j) g[j] = grid[j];
    float r1[11], r2[10], r3[9];
#pragma unroll
    for (int j = 0; j < 11; ++j) r1[j] = __builtin_amdgcn_rcpf(g[j + 1] - g[j] + EPSC);
#pragma unroll
    for (int j = 0; j < 10; ++j) r2[j] = __builtin_amdgcn_rcpf(g[j + 2] - g[j] + EPSC);
#pragma unroll
    for (int j = 0; j < 9;  ++j) r3[j] = __builtin_amdgcn_rcpf(g[j + 3] - g[j] + EPSC);

    float sw[4];
    float bs8[4][8];
#pragma unroll
    for (int e = 0; e < 4; ++e) {
        float xv = xv4[e];
        float bas[11];
#pragma unroll
        for (int j = 0; j < 11; ++j)
            bas[j] = (xv >= g[j] && xv < g[j + 1]) ? 1.0f : 0.0f;
#pragma unroll
        for (int j = 0; j < 10; ++j)
            bas[j] = (xv - g[j]) * r1[j] * bas[j] + (g[j + 2] - xv) * r1[j + 1] * bas[j + 1];
#pragma unroll
        for (int j = 0; j < 9; ++j)
            bas[j] = (xv - g[j]) * r2[j] * bas[j] + (g[j + 3] - xv) * r2[j + 1] * bas[j + 1];
#pragma unroll
        for (int j = 0; j < 8; ++j)
            bas[j] = (xv - g[j]) * r3[j] * bas[j] + (g[j + 4] - xv) * r3[j + 1] * bas[j + 1];
#pragma unroll
        for (int k = 0; k < 8; ++k) bs8[e][k] = bas[k];
        float sig = 1.0f / (1.0f + __expf(-xv));
        sw[e] = xv * sig;
    }

    bf16* outp = A + (size_t)b * KDIM + i0;
    *(bf16x4*)(outp) = (bf16x4){(bf16)sw[0], (bf16)sw[1], (bf16)sw[2], (bf16)sw[3]};
#pragma unroll
    for (int k = 0; k < 8; ++k)
        *(bf16x4*)(outp + (size_t)(k + 1) * 1024) =
            (bf16x4){(bf16)bs8[0][k], (bf16)bs8[1][k], (bf16)bs8[2][k], (bf16)bs8[3][k]};
}

// ---------------------------------------------------------------------------
// Kernel 2: Wt[o][j*1024+i] = { base_scaler[i,o], spline_weight[i,o,k]*spline_scaler[i,o] }
// ---------------------------------------------------------------------------
__global__ __launch_bounds__(256) void wprep_kernel(const float* __restrict__ w,
                                                    const float* __restrict__ ss,
                                                    const float* __restrict__ bs,
                                                    bf16* __restrict__ Wt) {
    int g = blockIdx.x * 256 + threadIdx.x;      // 1024 i * 128 o-groups = 131072
    int i  = g & 1023;
    int o0 = (g >> 10) << 3;                     // 8 o per thread
    size_t io0 = (size_t)i * 1024 + o0;
    f32x4 ssv0 = *(const f32x4*)(ss + io0);
    f32x4 ssv1 = *(const f32x4*)(ss + io0 + 4);
    f32x4 bsv0 = *(const f32x4*)(bs + io0);
    f32x4 bsv1 = *(const f32x4*)(bs + io0 + 4);
#pragma unroll
    for (int oo = 0; oo < 8; ++oo) {
        int o = o0 + oo;
        float scale = (oo < 4) ? ssv0[oo & 3] : ssv1[oo & 3];
        float base  = (oo < 4) ? bsv0[oo & 3] : bsv1[oo & 3];
        const float* wp = w + (io0 + oo) * 8;
        f32x4 w0 = *(const f32x4*)(wp);
        f32x4 w1 = *(const f32x4*)(wp + 4);

        bf16* outp = Wt + (size_t)o * KDIM + i;
        outp[0] = (bf16)base;
#pragma unroll
        for (int k = 0; k < 4; ++k) outp[(size_t)(k + 1) * 1024] = (bf16)(w0[k] * scale);
#pragma unroll
        for (int k = 0; k < 4; ++k) outp[(size_t)(k + 5) * 1024] = (bf16)(w1[k] * scale);
    }
}

// ---------------------------------------------------------------------------
// Kernel 3: GEMM  out = A(4096x9216) * Wt^T(1024x9216), bf16 MFMA 16x16x32.
// R14 = R12's proven schedule (256x256 tile, 8 waves 2Mx4N, BK=32, quad-buffer
// 128KB LDS, counted vmcnt(8) depth-3, 1 barrier/K-tile, reads-first order,
// setprio, identical staging pre-swizzle) with the MFMA shape swapped to
// 16x16x32 (R2's scheme): fragment reads span only 16 LDS rows (r15) ->
// 2 lanes/bank-span = 2-way = FREE (m136), vs 32x32's r31 span = 4-way.
// Every 32x32 variant measured exactly 7.08e6 conflict cycles; R2's 16x16
// measured 0. Per wave: 8x4 f32x4 acc, 12 b128 reads, 32 MFMA per K-tile.
// ---------------------------------------------------------------------------
__device__ __forceinline__ void load_lds16(const bf16* g, bf16* l) {
    __builtin_amdgcn_global_load_lds(
        (__attribute__((address_space(1))) void*)g,
        (__attribute__((address_space(3))) void*)l, 16, 0, 0);
}

__global__ __launch_bounds__(512, 2) void gemm_kernel(const bf16* __restrict__ A,
                                                      const bf16* __restrict__ Wt,
                                                      bf16* __restrict__ parts,
                                                      int split, int ktiles) {  // BK=32 units
    __shared__ __align__(16) bf16 SA[4][8192];   // 4 slots x 16KB (256 rows x 32 k)
    __shared__ __align__(16) bf16 SB[4][8192];

    const int t    = threadIdx.x;
    const int lane = t & 63;
    const int w    = t >> 6;           // 0..7

    // XCD-chunked decode: each XCD owns a contiguous L-range sharing tn panels.
    const int nwg8 = gridDim.x >> 3;
    const int L    = (blockIdx.x & 7) * nwg8 + (blockIdx.x >> 3);
    const int nper = split << 4;
    const int tn   = L / nper;
    const int rem  = L - tn * nper;
    const int s    = rem >> 4;
    const int tm   = rem & 15;

    const int row0 = tm << 8;
    const int col0 = tn << 8;
    const size_t k0 = (size_t)s * ktiles * 32;

    // ---- staging (linear LDS dest; pre-swizzled global source) ----
    // content(phys unit p, row r) = logical unit p ^ ((r>>1)&3)   [unchanged]
    const int sr = lane >> 2;                         // 0..15
    const int lc = (lane & 3) ^ ((lane >> 3) & 3);    // pre-swizzled 16B-unit
    const bf16* gA0 = A  + (size_t)(row0 + w * 16 + sr) * KDIM + k0 + lc * 8;
    const bf16* gB0 = Wt + (size_t)(col0 + w * 16 + sr) * KDIM + k0 + lc * 8;

    // ---- fragment read coords (16x16x32: 16 rows x 4 k-groups per frag) ----
    const int wm  = w >> 2;            // 0..1  (M half: 128 rows)
    const int wn  = w & 3;             // 0..3  (N quarter: 64 cols)
    const int r15 = lane & 15;
    const int g4  = lane >> 4;         // 0..3 k-group
    const int swb = (r15 >> 1) & 3;    // row bits 1-2 (tile offsets are mult of 16
                                       // -> (row>>1)&3 == (r15>>1)&3 for all tiles)
    const int cp  = ((g4 ^ swb) << 3); // swizzled element offset of this lane's unit

    f32x4 acc[8][4];
#pragma unroll
    for (int mt = 0; mt < 8; ++mt)
#pragma unroll
        for (int nt = 0; nt < 4; ++nt) acc[mt][nt] = (f32x4){0.f, 0.f, 0.f, 0.f};

    auto stage = [&](int j) {
        const int sl = j & 3;
        const bf16* pa = gA0 + (size_t)j * 32;
        const bf16* pb = gB0 + (size_t)j * 32;
        load_lds16(pa,                      &SA[sl][w * 512]);
        load_lds16(pa + (size_t)128 * KDIM, &SA[sl][4096 + w * 512]);
        load_lds16(pb,                      &SB[sl][w * 512]);
        load_lds16(pb + (size_t)128 * KDIM, &SB[sl][4096 + w * 512]);
    };

    // 12 frag reads in MFMA-need order: af0, all bv (reused by every mt), af1..af7.
    auto frag_load = [&](int sl, bf16x8 (&af)[8], bf16x8 (&bv)[4]) {
        af[0] = *(const bf16x8*)&SA[sl][(wm * 128 + 0 * 16 + r15) * 32 + cp];
#pragma unroll
        for (int nt = 0; nt < 4; ++nt)
            bv[nt] = *(const bf16x8*)&SB[sl][(wn * 64 + nt * 16 + r15) * 32 + cp];
#pragma unroll
        for (int mt = 1; mt < 8; ++mt)
            af[mt] = *(const bf16x8*)&SA[sl][(wm * 128 + mt * 16 + r15) * 32 + cp];
    };

    auto do_mfma = [&](bf16x8 (&af)[8], bf16x8 (&bv)[4]) {
        __builtin_amdgcn_s_setprio(1);
#pragma unroll
        for (int mt = 0; mt < 8; ++mt)
#pragma unroll
            for (int nt = 0; nt < 4; ++nt)
                acc[mt][nt] = __builtin_amdgcn_mfma_f32_16x16x32_bf16(
                    af[mt], bv[nt], acc[mt][nt], 0, 0, 0);
        __builtin_amdgcn_s_setprio(0);
    };

    // Prologue: 3 K-tiles in flight.
    stage(0); stage(1); stage(2);

    int j = 0;
    for (; j < ktiles - 3; ++j) {
        asm volatile("s_waitcnt vmcnt(8)" ::: "memory");   // tile j landed
        __builtin_amdgcn_s_barrier();                      // all waves see tile j
        asm volatile("" ::: "memory");                     // no read hoist above bar
        bf16x8 af[8], bv[4];
        frag_load(j & 3, af, bv);                          // reads issued FIRST
        stage(j + 3);                                      // then prefetch DMAs
        do_mfma(af, bv);                                   // compiler interleaves
    }
    {
        asm volatile("s_waitcnt vmcnt(8)" ::: "memory");
        __builtin_amdgcn_s_barrier();
        asm volatile("" ::: "memory");
        bf16x8 af[8], bv[4];
        frag_load(j & 3, af, bv);
        do_mfma(af, bv);
        ++j;
    }
    {
        asm volatile("s_waitcnt vmcnt(4)" ::: "memory");
        __builtin_amdgcn_s_barrier();
        asm volatile("" ::: "memory");
        bf16x8 af[8], bv[4];
        frag_load(j & 3, af, bv);
        do_mfma(af, bv);
        ++j;
    }
    {
        asm volatile("s_waitcnt vmcnt(0)" ::: "memory");
        __builtin_amdgcn_s_barrier();
        asm volatile("" ::: "memory");
        bf16x8 af[8], bv[4];
        frag_load(j & 3, af, bv);
        do_mfma(af, bv);
    }

    // Epilogue (UNIFORM): bf16 partial for every split s.
    // 16x16 C/D layout: col = lane&15, row = (lane>>4)*4 + reg   [m89]
    bf16* cp2 = parts + (size_t)s * BATCH * O_F
              + (size_t)(row0 + wm * 128) * O_F + col0 + wn * 64 + r15;
#pragma unroll
    for (int mt = 0; mt < 8; ++mt)
#pragma unroll
        for (int nt = 0; nt < 4; ++nt)
#pragma unroll
            for (int r = 0; r < 4; ++r)
                cp2[(size_t)(mt * 16 + g4 * 4 + r) * O_F + nt * 16] = (bf16)acc[mt][nt][r];
}

// ---------------------------------------------------------------------------
// Kernel 4: out = sum(parts[0..np))   (split-K reduce), bf16 partials -> f32
// ---------------------------------------------------------------------------
__global__ __launch_bounds__(256) void add_kernel(float* __restrict__ out,
                                                  const bf16* __restrict__ parts,
                                                  int np) {
    int t = blockIdx.x * 256 + threadIdx.x;      // 1,048,576 threads, 4 f32 each
    f32x4 a = {0.f, 0.f, 0.f, 0.f};
    for (int p = 0; p < np; ++p) {
        bf16x4 b = *((const bf16x4*)(parts + (size_t)p * BATCH * O_F) + t);
#pragma unroll
        for (int e = 0; e < 4; ++e) a[e] += (float)b[e];
    }
    *((f32x4*)out + t) = a;
}

// ---------------------------------------------------------------------------
extern "C" void kernel_launch(void* const* d_in, const int* in_sizes, int n_in,
                              void* d_out, int out_size, void* d_ws, size_t ws_size,
                              hipStream_t stream) {
    const float* x    = (const float*)d_in[0];
    const float* grid = (const float*)d_in[1];
    const float* w    = (const float*)d_in[2];
    const float* ss   = (const float*)d_in[3];
    const float* bs   = (const float*)d_in[4];
    float* out = (float*)d_out;

    const size_t nA = (size_t)BATCH * KDIM * 2;   // 75.5 MB
    const size_t nW = (size_t)O_F   * KDIM * 2;   // 18.9 MB
    const size_t nP = (size_t)BATCH * O_F  * 2;   // 8.39 MB per bf16 partial

    bf16* A  = (bf16*)d_ws;
    bf16* Wt = (bf16*)((char*)d_ws + nA);
    bf16* parts = (bf16*)((char*)d_ws + nA + nW);

    act_kernel<<<(BATCH * I_F / 4) / 256, 256, 0, stream>>>(x, grid, A);
    wprep_kernel<<<(I_F * O_F / 8) / 256, 256, 0, stream>>>(w, ss, bs, Wt);

    int split = (ws_size >= nA + nW + 4 * nP) ? 4
              : (ws_size >= nA + nW + 2 * nP) ? 2 : 1;
    gemm_kernel<<<64 * split, 512, 0, stream>>>(A, Wt, parts, split, 288 / split);
    add_kernel<<<(BATCH * O_F / 4) / 256, 256, 0, stream>>>(out, parts, split);
}

// Round 16
// 109.560 us; speedup vs baseline: 1.3603x; 1.0831x over previous
//
#include <hip/hip_runtime.h>
#include <hip/hip_bf16.h>
#include <cstdint>
#include <cstddef>

#define I_F   1024
#define O_F   1024
#define BATCH 4096
#define KDIM  9216   // 9 * 1024 : j-major (j=0 base/swish, j=1..8 spline bases)
#define EPSC  1e-7f

typedef __bf16 bf16;
typedef __bf16 bf16x4 __attribute__((ext_vector_type(4)));
typedef __bf16 bf16x8 __attribute__((ext_vector_type(8)));
typedef float  f32x4  __attribute__((ext_vector_type(4)));

// ---------------------------------------------------------------------------
// Kernel 1 (fused prep): blocks [0,512) -> weight prep, [512,4608) -> acts.
// ---------------------------------------------------------------------------
__global__ __launch_bounds__(256) void prep_kernel(const float* __restrict__ x,
                                                   const float* __restrict__ grid,
                                                   const float* __restrict__ w,
                                                   const float* __restrict__ ss,
                                                   const float* __restrict__ bs,
                                                   bf16* __restrict__ A,
                                                   bf16* __restrict__ Wt) {
    if (blockIdx.x < 512) {
        // ---- weight prep ----
        int g = blockIdx.x * 256 + threadIdx.x;      // 131072 threads
        int i  = g & 1023;
        int o0 = (g >> 10) << 3;                     // 8 o per thread
        size_t io0 = (size_t)i * 1024 + o0;
        f32x4 ssv0 = *(const f32x4*)(ss + io0);
        f32x4 ssv1 = *(const f32x4*)(ss + io0 + 4);
        f32x4 bsv0 = *(const f32x4*)(bs + io0);
        f32x4 bsv1 = *(const f32x4*)(bs + io0 + 4);
#pragma unroll
        for (int oo = 0; oo < 8; ++oo) {
            int o = o0 + oo;
            float scale = (oo < 4) ? ssv0[oo & 3] : ssv1[oo & 3];
            float base  = (oo < 4) ? bsv0[oo & 3] : bsv1[oo & 3];
            const float* wp = w + (io0 + oo) * 8;
            f32x4 w0 = *(const f32x4*)(wp);
            f32x4 w1 = *(const f32x4*)(wp + 4);

            bf16* outp = Wt + (size_t)o * KDIM + i;
            outp[0] = (bf16)base;
#pragma unroll
            for (int k = 0; k < 4; ++k) outp[(size_t)(k + 1) * 1024] = (bf16)(w0[k] * scale);
#pragma unroll
            for (int k = 0; k < 4; ++k) outp[(size_t)(k + 5) * 1024] = (bf16)(w1[k] * scale);
        }
    } else {
        // ---- activations ----
        int t  = (blockIdx.x - 512) * 256 + threadIdx.x;  // 1,048,576 threads
        int b  = t >> 8;
        int i0 = (t & 255) << 2;
        f32x4 xv4 = *(const f32x4*)(x + (size_t)b * I_F + i0);

        float g[12];
#pragma unroll
        for (int j = 0; j < 12; ++j) g[j] = grid[j];
        float r1[11], r2[10], r3[9];
#pragma unroll
        for (int j = 0; j < 11; ++j) r1[j] = __builtin_amdgcn_rcpf(g[j + 1] - g[j] + EPSC);
#pragma unroll
        for (int j = 0; j < 10; ++j) r2[j] = __builtin_amdgcn_rcpf(g[j + 2] - g[j] + EPSC);
#pragma unroll
        for (int j = 0; j < 9;  ++j) r3[j] = __builtin_amdgcn_rcpf(g[j + 3] - g[j] + EPSC);

        float sw[4];
        float bs8[4][8];
#pragma unroll
        for (int e = 0; e < 4; ++e) {
            float xv = xv4[e];
            float bas[11];
#pragma unroll
            for (int j = 0; j < 11; ++j)
                bas[j] = (xv >= g[j] && xv < g[j + 1]) ? 1.0f : 0.0f;
#pragma unroll
            for (int j = 0; j < 10; ++j)
                bas[j] = (xv - g[j]) * r1[j] * bas[j] + (g[j + 2] - xv) * r1[j + 1] * bas[j + 1];
#pragma unroll
            for (int j = 0; j < 9; ++j)
                bas[j] = (xv - g[j]) * r2[j] * bas[j] + (g[j + 3] - xv) * r2[j + 1] * bas[j + 1];
#pragma unroll
            for (int j = 0; j < 8; ++j)
                bas[j] = (xv - g[j]) * r3[j] * bas[j] + (g[j + 4] - xv) * r3[j + 1] * bas[j + 1];
#pragma unroll
            for (int k = 0; k < 8; ++k) bs8[e][k] = bas[k];
            float sig = 1.0f / (1.0f + __expf(-xv));
            sw[e] = xv * sig;
        }

        bf16* outp = A + (size_t)b * KDIM + i0;
        *(bf16x4*)(outp) = (bf16x4){(bf16)sw[0], (bf16)sw[1], (bf16)sw[2], (bf16)sw[3]};
#pragma unroll
        for (int k = 0; k < 8; ++k)
            *(bf16x4*)(outp + (size_t)(k + 1) * 1024) =
                (bf16x4){(bf16)bs8[0][k], (bf16)bs8[1][k], (bf16)bs8[2][k], (bf16)bs8[3][k]};
    }
}

// ---------------------------------------------------------------------------
// Kernel 2: GEMM  out = A(4096x9216) * Wt^T(1024x9216), bf16 MFMA 16x16x32.
// R16 = R14's proven loose schedule at BK=64, DOUBLE-buffer (2x32KB x2 =
// 128KB, legal). Halves sync points (72 -> 36). Per-tile vmcnt(0) waits on
// DMAs issued one full tile (~2600cy) earlier -> pre-drained. Slot safety:
// stage(j+1) targets slot last read at tile j-1; all waves' tile-(j-1) reads
// complete before they cross tile j's barrier. Read pattern: byte =
// r*128 + 16*((ks*4+g4)^(r15&7)) -> 8 spans x 8 lanes, uniform 8 words/bank
// = wave-b128 floor (same class as R14's measured-zero). Staging pre-swizzle
// lc=(lane&7)^(lane>>3) (R7-proven involution for 8-row x 8-unit DMA).
// ---------------------------------------------------------------------------
__device__ __forceinline__ void load_lds16(const bf16* g, bf16* l) {
    __builtin_amdgcn_global_load_lds(
        (__attribute__((address_space(1))) void*)g,
        (__attribute__((address_space(3))) void*)l, 16, 0, 0);
}

__global__ __launch_bounds__(512, 1) void gemm_kernel(const bf16* __restrict__ A,
                                                      const bf16* __restrict__ Wt,
                                                      bf16* __restrict__ parts,
                                                      int split, int ktiles) {  // BK=64 units
    __shared__ __align__(16) bf16 SA[2][16384];   // 2 slots x 32KB (256 rows x 64 k)
    __shared__ __align__(16) bf16 SB[2][16384];

    const int t    = threadIdx.x;
    const int lane = t & 63;
    const int w    = t >> 6;           // 0..7

    // XCD-chunked decode: each XCD owns a contiguous L-range sharing tn panels.
    const int nwg8 = gridDim.x >> 3;
    const int L    = (blockIdx.x & 7) * nwg8 + (blockIdx.x >> 3);
    const int nper = split << 4;
    const int tn   = L / nper;
    const int rem  = L - tn * nper;
    const int s    = rem >> 4;
    const int tm   = rem & 15;

    const int row0 = tm << 8;
    const int col0 = tn << 8;
    const size_t k0 = (size_t)s * ktiles * 64;

    // ---- staging (linear LDS dest; pre-swizzled global source) ----
    // DMA instr covers 8 rows x 8 16B-units; lane l -> row +(l>>3), phys unit l&7.
    // content(phys p, row r) = logical unit p ^ (r&7)  ->  lc = (l&7) ^ (l>>3).
    const int sr8 = lane >> 3;                        // 0..7
    const int lc  = (lane & 7) ^ sr8;                 // pre-swizzled 16B-unit
    const bf16* gA0 = A  + (size_t)(row0 + w * 32 + sr8) * KDIM + k0 + lc * 8;
    const bf16* gB0 = Wt + (size_t)(col0 + w * 32 + sr8) * KDIM + k0 + lc * 8;

    // ---- fragment read coords (16x16x32, K=64 -> 2 ks slices) ----
    const int wm  = w >> 2;            // 0..1  (M half: 128 rows)
    const int wn  = w & 3;             // 0..3  (N quarter: 64 cols)
    const int r15 = lane & 15;
    const int g4  = lane >> 4;         // 0..3 k-group within a K=32 slice
    const int rx7 = r15 & 7;           // row&7 (frag bases are mult of 16)

    f32x4 acc[8][4];
#pragma unroll
    for (int mt = 0; mt < 8; ++mt)
#pragma unroll
        for (int nt = 0; nt < 4; ++nt) acc[mt][nt] = (f32x4){0.f, 0.f, 0.f, 0.f};

    auto stage = [&](int j) {
        const int sl = j & 1;
        const bf16* pa = gA0 + (size_t)j * 64;
        const bf16* pb = gB0 + (size_t)j * 64;
#pragma unroll
        for (int q = 0; q < 4; ++q)
            load_lds16(pa + (size_t)(q * 8) * KDIM, &SA[sl][(w * 32 + q * 8) * 64]);
#pragma unroll
        for (int q = 0; q < 4; ++q)
            load_lds16(pb + (size_t)(q * 8) * KDIM, &SB[sl][(w * 32 + q * 8) * 64]);
    };

    // 12 frag reads (need-order) for one K=32 slice.
    auto frag_load = [&](int sl, int ks, bf16x8 (&af)[8], bf16x8 (&bv)[4]) {
        const int cp = (((ks * 4 + g4) ^ rx7) << 3);
        af[0] = *(const bf16x8*)&SA[sl][(wm * 128 + 0 * 16 + r15) * 64 + cp];
#pragma unroll
        for (int nt = 0; nt < 4; ++nt)
            bv[nt] = *(const bf16x8*)&SB[sl][(wn * 64 + nt * 16 + r15) * 64 + cp];
#pragma unroll
        for (int mt = 1; mt < 8; ++mt)
            af[mt] = *(const bf16x8*)&SA[sl][(wm * 128 + mt * 16 + r15) * 64 + cp];
    };

    auto do_mfma = [&](bf16x8 (&af)[8], bf16x8 (&bv)[4]) {
        __builtin_amdgcn_s_setprio(1);
#pragma unroll
        for (int mt = 0; mt < 8; ++mt)
#pragma unroll
            for (int nt = 0; nt < 4; ++nt)
                acc[mt][nt] = __builtin_amdgcn_mfma_f32_16x16x32_bf16(
                    af[mt], bv[nt], acc[mt][nt], 0, 0, 0);
        __builtin_amdgcn_s_setprio(0);
    };

    // Prologue: tile 0 in flight.
    stage(0);

    for (int j = 0; j < ktiles; ++j) {
        asm volatile("s_waitcnt vmcnt(0)" ::: "memory");   // tile j landed (issued 1 tile ago)
        __builtin_amdgcn_s_barrier();                      // all waves see tile j
        asm volatile("" ::: "memory");                     // no read hoist above bar
        bf16x8 af0[8], bv0[4], af1[8], bv1[4];
        frag_load(j & 1, 0, af0, bv0);                     // ks0 reads FIRST
        if (j + 1 < ktiles) stage(j + 1);                  // into slot read at j-1 (safe)
        do_mfma(af0, bv0);                                 // ks1 reads issue under this
        frag_load(j & 1, 1, af1, bv1);
        do_mfma(af1, bv1);
    }

    // Epilogue (UNIFORM): bf16 partial for every split s.
    // 16x16 C/D layout: col = lane&15, row = (lane>>4)*4 + reg   [m89]
    bf16* cp2 = parts + (size_t)s * BATCH * O_F
              + (size_t)(row0 + wm * 128) * O_F + col0 + wn * 64 + r15;
#pragma unroll
    for (int mt = 0; mt < 8; ++mt)
#pragma unroll
        for (int nt = 0; nt < 4; ++nt)
#pragma unroll
            for (int r = 0; r < 4; ++r)
                cp2[(size_t)(mt * 16 + g4 * 4 + r) * O_F + nt * 16] = (bf16)acc[mt][nt][r];
}

// ---------------------------------------------------------------------------
// Kernel 3: out = sum(parts[0..np))   (split-K reduce), bf16 partials -> f32
// ---------------------------------------------------------------------------
__global__ __launch_bounds__(256) void add_kernel(float* __restrict__ out,
                                                  const bf16* __restrict__ parts,
                                                  int np) {
    int t = blockIdx.x * 256 + threadIdx.x;      // 1,048,576 threads, 4 f32 each
    f32x4 a = {0.f, 0.f, 0.f, 0.f};
    for (int p = 0; p < np; ++p) {
        bf16x4 b = *((const bf16x4*)(parts + (size_t)p * BATCH * O_F) + t);
#pragma unroll
        for (int e = 0; e < 4; ++e) a[e] += (float)b[e];
    }
    *((f32x4*)out + t) = a;
}

// ---------------------------------------------------------------------------
extern "C" void kernel_launch(void* const* d_in, const int* in_sizes, int n_in,
                              void* d_out, int out_size, void* d_ws, size_t ws_size,
                              hipStream_t stream) {
    const float* x    = (const float*)d_in[0];
    const float* grid = (const float*)d_in[1];
    const float* w    = (const float*)d_in[2];
    const float* ss   = (const float*)d_in[3];
    const float* bs   = (const float*)d_in[4];
    float* out = (float*)d_out;

    const size_t nA = (size_t)BATCH * KDIM * 2;   // 75.5 MB
    const size_t nW = (size_t)O_F   * KDIM * 2;   // 18.9 MB
    const size_t nP = (size_t)BATCH * O_F  * 2;   // 8.39 MB per bf16 partial

    bf16* A  = (bf16*)d_ws;
    bf16* Wt = (bf16*)((char*)d_ws + nA);
    bf16* parts = (bf16*)((char*)d_ws + nA + nW);

    prep_kernel<<<4608, 256, 0, stream>>>(x, grid, w, ss, bs, A, Wt);

    int split = (ws_size >= nA + nW + 4 * nP) ? 4
              : (ws_size >= nA + nW + 2 * nP) ? 2 : 1;
    // ktiles in BK=64 units: 9216/64 = 144 total
    gemm_kernel<<<64 * split, 512, 0, stream>>>(A, Wt, parts, split, 144 / split);
    add_kernel<<<(BATCH * O_F / 4) / 256, 256, 0, stream>>>(out, parts, split);
}

// Round 17
// 109.410 us; speedup vs baseline: 1.3622x; 1.0014x over previous
//
#include <hip/hip_runtime.h>
#include <hip/hip_bf16.h>
#include <cstdint>
#include <cstddef>

#define I_F   1024
#define O_F   1024
#define BATCH 4096
#define KDIM  9216   // 9 * 1024 : j-major (j=0 base/swish, j=1..8 spline bases)
#define EPSC  1e-7f

typedef __bf16 bf16;
typedef __bf16 bf16x4 __attribute__((ext_vector_type(4)));
typedef __bf16 bf16x8 __attribute__((ext_vector_type(8)));
typedef float  f32x4  __attribute__((ext_vector_type(4)));

// ---------------------------------------------------------------------------
// Kernel 1 (fused prep): blocks [0,512) -> weight prep, [512,4608) -> acts.
// ---------------------------------------------------------------------------
__global__ __launch_bounds__(256) void prep_kernel(const float* __restrict__ x,
                                                   const float* __restrict__ grid,
                                                   const float* __restrict__ w,
                                                   const float* __restrict__ ss,
                                                   const float* __restrict__ bs,
                                                   bf16* __restrict__ A,
                                                   bf16* __restrict__ Wt) {
    if (blockIdx.x < 512) {
        // ---- weight prep ----
        int g = blockIdx.x * 256 + threadIdx.x;      // 131072 threads
        int i  = g & 1023;
        int o0 = (g >> 10) << 3;                     // 8 o per thread
        size_t io0 = (size_t)i * 1024 + o0;
        f32x4 ssv0 = *(const f32x4*)(ss + io0);
        f32x4 ssv1 = *(const f32x4*)(ss + io0 + 4);
        f32x4 bsv0 = *(const f32x4*)(bs + io0);
        f32x4 bsv1 = *(const f32x4*)(bs + io0 + 4);
#pragma unroll
        for (int oo = 0; oo < 8; ++oo) {
            int o = o0 + oo;
            float scale = (oo < 4) ? ssv0[oo & 3] : ssv1[oo & 3];
            float base  = (oo < 4) ? bsv0[oo & 3] : bsv1[oo & 3];
            const float* wp = w + (io0 + oo) * 8;
            f32x4 w0 = *(const f32x4*)(wp);
            f32x4 w1 = *(const f32x4*)(wp + 4);

            bf16* outp = Wt + (size_t)o * KDIM + i;
            outp[0] = (bf16)base;
#pragma unroll
            for (int k = 0; k < 4; ++k) outp[(size_t)(k + 1) * 1024] = (bf16)(w0[k] * scale);
#pragma unroll
            for (int k = 0; k < 4; ++k) outp[(size_t)(k + 5) * 1024] = (bf16)(w1[k] * scale);
        }
    } else {
        // ---- activations ----
        int t  = (blockIdx.x - 512) * 256 + threadIdx.x;  // 1,048,576 threads
        int b  = t >> 8;
        int i0 = (t & 255) << 2;
        f32x4 xv4 = *(const f32x4*)(x + (size_t)b * I_F + i0);

        float g[12];
#pragma unroll
        for (int j = 0; j < 12; ++j) g[j] = grid[j];
        float r1[11], r2[10], r3[9];
#pragma unroll
        for (int j = 0; j < 11; ++j) r1[j] = __builtin_amdgcn_rcpf(g[j + 1] - g[j] + EPSC);
#pragma unroll
        for (int j = 0; j < 10; ++j) r2[j] = __builtin_amdgcn_rcpf(g[j + 2] - g[j] + EPSC);
#pragma unroll
        for (int j = 0; j < 9;  ++j) r3[j] = __builtin_amdgcn_rcpf(g[j + 3] - g[j] + EPSC);

        float sw[4];
        float bs8[4][8];
#pragma unroll
        for (int e = 0; e < 4; ++e) {
            float xv = xv4[e];
            float bas[11];
#pragma unroll
            for (int j = 0; j < 11; ++j)
                bas[j] = (xv >= g[j] && xv < g[j + 1]) ? 1.0f : 0.0f;
#pragma unroll
            for (int j = 0; j < 10; ++j)
                bas[j] = (xv - g[j]) * r1[j] * bas[j] + (g[j + 2] - xv) * r1[j + 1] * bas[j + 1];
#pragma unroll
            for (int j = 0; j < 9; ++j)
                bas[j] = (xv - g[j]) * r2[j] * bas[j] + (g[j + 3] - xv) * r2[j + 1] * bas[j + 1];
#pragma unroll
            for (int j = 0; j < 8; ++j)
                bas[j] = (xv - g[j]) * r3[j] * bas[j] + (g[j + 4] - xv) * r3[j + 1] * bas[j + 1];
#pragma unroll
            for (int k = 0; k < 8; ++k) bs8[e][k] = bas[k];
            float sig = 1.0f / (1.0f + __expf(-xv));
            sw[e] = xv * sig;
        }

        bf16* outp = A + (size_t)b * KDIM + i0;
        *(bf16x4*)(outp) = (bf16x4){(bf16)sw[0], (bf16)sw[1], (bf16)sw[2], (bf16)sw[3]};
#pragma unroll
        for (int k = 0; k < 8; ++k)
            *(bf16x4*)(outp + (size_t)(k + 1) * 1024) =
                (bf16x4){(bf16)bs8[0][k], (bf16)bs8[1][k], (bf16)bs8[2][k], (bf16)bs8[3][k]};
    }
}

// ---------------------------------------------------------------------------
// Kernel 2: GEMM  out = A(4096x9216) * Wt^T(1024x9216), bf16 MFMA 16x16x32.
// R17 = R16 (BK=64 double-buffer, counted-by-construction vmcnt, 1 barrier
// per tile, reads-first, 0-conflict read/staging swizzle pair) + WAVE-PARITY
// ANTI-PHASE: even waves process k-slices (0,1), odd waves (1,0). When a
// SIMD's even wave runs its 32-MFMA burst, the odd wave's 12 ds_reads are
// served -> LDS port and MFMA pipe concurrently busy (R16 ledger showed them
// phase-additive: wall 4810 = LDS 2816 + MFMA 2483 per tile). Parity is a
// RUNTIME index so the compiler can't merge the phases. fp32 acc order
// changes per-wave only (deterministic).
// ---------------------------------------------------------------------------
__device__ __forceinline__ void load_lds16(const bf16* g, bf16* l) {
    __builtin_amdgcn_global_load_lds(
        (__attribute__((address_space(1))) void*)g,
        (__attribute__((address_space(3))) void*)l, 16, 0, 0);
}

__global__ __launch_bounds__(512, 1) void gemm_kernel(const bf16* __restrict__ A,
                                                      const bf16* __restrict__ Wt,
                                                      bf16* __restrict__ parts,
                                                      int split, int ktiles) {  // BK=64 units
    __shared__ __align__(16) bf16 SA[2][16384];   // 2 slots x 32KB (256 rows x 64 k)
    __shared__ __align__(16) bf16 SB[2][16384];

    const int t    = threadIdx.x;
    const int lane = t & 63;
    const int w    = t >> 6;           // 0..7

    // XCD-chunked decode: each XCD owns a contiguous L-range sharing tn panels.
    const int nwg8 = gridDim.x >> 3;
    const int L    = (blockIdx.x & 7) * nwg8 + (blockIdx.x >> 3);
    const int nper = split << 4;
    const int tn   = L / nper;
    const int rem  = L - tn * nper;
    const int s    = rem >> 4;
    const int tm   = rem & 15;

    const int row0 = tm << 8;
    const int col0 = tn << 8;
    const size_t k0 = (size_t)s * ktiles * 64;

    // ---- staging (linear LDS dest; pre-swizzled global source) ----
    // DMA instr covers 8 rows x 8 16B-units; lane l -> row +(l>>3), phys unit l&7.
    // content(phys p, row r) = logical unit p ^ (r&7)  ->  lc = (l&7) ^ (l>>3).
    const int sr8 = lane >> 3;                        // 0..7
    const int lc  = (lane & 7) ^ sr8;                 // pre-swizzled 16B-unit
    const bf16* gA0 = A  + (size_t)(row0 + w * 32 + sr8) * KDIM + k0 + lc * 8;
    const bf16* gB0 = Wt + (size_t)(col0 + w * 32 + sr8) * KDIM + k0 + lc * 8;

    // ---- fragment read coords (16x16x32, K=64 -> 2 ks slices) ----
    const int wm  = w >> 2;            // 0..1  (M half: 128 rows)
    const int wn  = w & 3;             // 0..3  (N quarter: 64 cols)
    const int r15 = lane & 15;
    const int g4  = lane >> 4;         // 0..3 k-group within a K=32 slice
    const int rx7 = r15 & 7;           // row&7 (frag bases are mult of 16)
    const int ks0 = w & 1;             // wave-parity anti-phase (RUNTIME)

    f32x4 acc[8][4];
#pragma unroll
    for (int mt = 0; mt < 8; ++mt)
#pragma unroll
        for (int nt = 0; nt < 4; ++nt) acc[mt][nt] = (f32x4){0.f, 0.f, 0.f, 0.f};

    auto stage = [&](int j) {
        const int sl = j & 1;
        const bf16* pa = gA0 + (size_t)j * 64;
        const bf16* pb = gB0 + (size_t)j * 64;
#pragma unroll
        for (int q = 0; q < 4; ++q)
            load_lds16(pa + (size_t)(q * 8) * KDIM, &SA[sl][(w * 32 + q * 8) * 64]);
#pragma unroll
        for (int q = 0; q < 4; ++q)
            load_lds16(pb + (size_t)(q * 8) * KDIM, &SB[sl][(w * 32 + q * 8) * 64]);
    };

    // 12 frag reads (need-order) for one K=32 slice.
    auto frag_load = [&](int sl, int ks, bf16x8 (&af)[8], bf16x8 (&bv)[4]) {
        const int cp = (((ks * 4 + g4) ^ rx7) << 3);
        af[0] = *(const bf16x8*)&SA[sl][(wm * 128 + 0 * 16 + r15) * 64 + cp];
#pragma unroll
        for (int nt = 0; nt < 4; ++nt)
            bv[nt] = *(const bf16x8*)&SB[sl][(wn * 64 + nt * 16 + r15) * 64 + cp];
#pragma unroll
        for (int mt = 1; mt < 8; ++mt)
            af[mt] = *(const bf16x8*)&SA[sl][(wm * 128 + mt * 16 + r15) * 64 + cp];
    };

    auto do_mfma = [&](bf16x8 (&af)[8], bf16x8 (&bv)[4]) {
        __builtin_amdgcn_s_setprio(1);
#pragma unroll
        for (int mt = 0; mt < 8; ++mt)
#pragma unroll
            for (int nt = 0; nt < 4; ++nt)
                acc[mt][nt] = __builtin_amdgcn_mfma_f32_16x16x32_bf16(
                    af[mt], bv[nt], acc[mt][nt], 0, 0, 0);
        __builtin_amdgcn_s_setprio(0);
    };

    // Prologue: tile 0 in flight.
    stage(0);

    for (int j = 0; j < ktiles; ++j) {
        asm volatile("s_waitcnt vmcnt(0)" ::: "memory");   // tile j landed (issued 1 tile ago)
        __builtin_amdgcn_s_barrier();                      // all waves see tile j
        asm volatile("" ::: "memory");                     // no read hoist above bar
        bf16x8 afA[8], bvA[4], afB[8], bvB[4];
        frag_load(j & 1, ks0, afA, bvA);                   // this wave's FIRST slice
        if (j + 1 < ktiles) stage(j + 1);                  // into slot read at j-1 (safe)
        do_mfma(afA, bvA);                                 // odd waves' reads overlap this
        frag_load(j & 1, ks0 ^ 1, afB, bvB);               // SECOND slice
        do_mfma(afB, bvB);
    }

    // Epilogue (UNIFORM): bf16 partial for every split s.
    // 16x16 C/D layout: col = lane&15, row = (lane>>4)*4 + reg   [m89]
    bf16* cp2 = parts + (size_t)s * BATCH * O_F
              + (size_t)(row0 + wm * 128) * O_F + col0 + wn * 64 + r15;
#pragma unroll
    for (int mt = 0; mt < 8; ++mt)
#pragma unroll
        for (int nt = 0; nt < 4; ++nt)
#pragma unroll
            for (int r = 0; r < 4; ++r)
                cp2[(size_t)(mt * 16 + g4 * 4 + r) * O_F + nt * 16] = (bf16)acc[mt][nt][r];
}

// ---------------------------------------------------------------------------
// Kernel 3: out = sum(parts[0..np))   (split-K reduce), bf16 partials -> f32
// ---------------------------------------------------------------------------
__global__ __launch_bounds__(256) void add_kernel(float* __restrict__ out,
                                                  const bf16* __restrict__ parts,
                                                  int np) {
    int t = blockIdx.x * 256 + threadIdx.x;      // 1,048,576 threads, 4 f32 each
    f32x4 a = {0.f, 0.f, 0.f, 0.f};
    for (int p = 0; p < np; ++p) {
        bf16x4 b = *((const bf16x4*)(parts + (size_t)p * BATCH * O_F) + t);
#pragma unroll
        for (int e = 0; e < 4; ++e) a[e] += (float)b[e];
    }
    *((f32x4*)out + t) = a;
}

// ---------------------------------------------------------------------------
extern "C" void kernel_launch(void* const* d_in, const int* in_sizes, int n_in,
                              void* d_out, int out_size, void* d_ws, size_t ws_size,
                              hipStream_t stream) {
    const float* x    = (const float*)d_in[0];
    const float* grid = (const float*)d_in[1];
    const float* w    = (const float*)d_in[2];
    const float* ss   = (const float*)d_in[3];
    const float* bs   = (const float*)d_in[4];
    float* out = (float*)d_out;

    const size_t nA = (size_t)BATCH * KDIM * 2;   // 75.5 MB
    const size_t nW = (size_t)O_F   * KDIM * 2;   // 18.9 MB
    const size_t nP = (size_t)BATCH * O_F  * 2;   // 8.39 MB per bf16 partial

    bf16* A  = (bf16*)d_ws;
    bf16* Wt = (bf16*)((char*)d_ws + nA);
    bf16* parts = (bf16*)((char*)d_ws + nA + nW);

    prep_kernel<<<4608, 256, 0, stream>>>(x, grid, w, ss, bs, A, Wt);

    int split = (ws_size >= nA + nW + 4 * nP) ? 4
              : (ws_size >= nA + nW + 2 * nP) ? 2 : 1;
    // ktiles in BK=64 units: 9216/64 = 144 total
    gemm_kernel<<<64 * split, 512, 0, stream>>>(A, Wt, parts, split, 144 / split);
    add_kernel<<<(BATCH * O_F / 4) / 256, 256, 0, stream>>>(out, parts, split);
}